// Round 13
// baseline (340.981 us; speedup 1.0000x reference)
//
#include <hip/hip_runtime.h>

typedef unsigned short u16;
typedef unsigned int u32;
typedef __attribute__((ext_vector_type(8))) short bf8;   // 8 bf16 (4 VGPRs)
typedef __attribute__((ext_vector_type(4))) float f4;    // MFMA C/D frag
typedef __attribute__((ext_vector_type(4))) int i4;

#define NB  30
#define BG  2048
#define EPG 240
#define NEg (BG*EPG)
#define SA  260     // A row stride (shorts): 130 dw -> uniform 2-way banks
#define SS  40      // S row stride
#define SL  264     // latent row stride (heads)
#define SG  1032    // head G-stage row stride (shorts)

// workspace offsets (bytes). W tensors fragment-major (swizzled):
// chunk(wave,ktf,nt) = ((wave*(K/32)+ktf)*4+nt)*512 u16, elem = lane*8+j,
// value = W^T[wave*64+nt*16+(lane&15)][ktf*32+(lane>>4)*8+j]
#define WOFF_WT    0                         // [3][256][512] bf16
#define WOFF_WAGG  786432                    // [256][1024] bf16
#define WOFF_WMU   (786432+524288)           // [256][256] bf16
#define WOFF_WVAR  (786432+524288+131072)
#define WOFF_TAB   (786432+524288+262144)    // fp32 tables: 12032 floats
#define WOFF_G     (WOFF_TAB + 48128)        // g bf16 [2048][1024]
#define WOFF_FLAG  (WOFF_G + 4194304)        // 2 ints

__device__ __forceinline__ float us2f(u16 u) {
    union { u32 i; float f; } v; v.i = ((u32)u) << 16; return v.f;
}
__device__ __forceinline__ u16 f2us(float f) {
    union { float f; u32 u; } v; v.f = f;
    u32 u = v.u;
    return (u16)((u + 0x7FFFu + ((u >> 16) & 1u)) >> 16);   // RNE
}
__device__ __forceinline__ int ldidx(const void* p, long long i, int i64) {
    return i64 ? (int)((const long long*)p)[i] : ((const int*)p)[i];
}

// ---------------------------------------------------------------------------
// Prep (210 blocks): tile transposes -> swizzled fragment-major bf16,
// fp32 encoder tables (192..208), dtype probe (209).
// ---------------------------------------------------------------------------
__global__ __launch_bounds__(256) void prep_kernel(
    const float* __restrict__ Wmp1, const float* __restrict__ Wmp2,
    const float* __restrict__ Wmp3, const float* __restrict__ Wagg,
    const float* __restrict__ Wmu,  const float* __restrict__ Wvar,
    const float* __restrict__ W_geo, const float* __restrict__ b_geo,
    const float* __restrict__ emb,   const float* __restrict__ W_lot,
    const float* __restrict__ b_lot,
    const void* __restrict__ edge,  const void* __restrict__ semA,
    char* __restrict__ ws, int* __restrict__ flags)
{
    const int t = threadIdx.x;
    const int b = blockIdx.x;

    if (b == 209) {                    // probe
        if (t == 0) {
            const int* e32 = (const int*)edge;
            int zc = 0;
            for (int j = 1; j <= 31; j += 2) if (e32[j] == 0) zc++;
            flags[0] = (zc == 16) ? 1 : 0;
            flags[1] = 0;
        }
        return;
    }

    if (b >= 192) {                    // tables (exact fp32 algebra)
        float* tab = (float*)(ws + WOFF_TAB);
        const int d = t, b2 = b - 192;
        if (b2 < 5) {
            float a = 0.f;
            #pragma unroll 8
            for (int k = 0; k < 256; ++k)
                a = fmaf(W_geo[b2*256 + k], W_lot[k*256 + d], a);
            tab[b2*256 + d] = a;
        } else if (b2 < 16) {
            const int s = b2 - 5;
            float a = 0.f;
            #pragma unroll 8
            for (int k = 0; k < 256; ++k)
                a = fmaf(emb[s*256 + k], W_lot[(256 + k)*256 + d], a);
            tab[1536 + s*256 + d] = a;
        } else {
            float a = b_lot[d];
            #pragma unroll 8
            for (int k = 0; k < 256; ++k)
                a = fmaf(b_geo[k], W_lot[k*256 + d], a);
            tab[1280 + d] = a;
            for (int p = 0; p < NB; ++p)
                tab[4352 + p*256 + d] = W_lot[(512 + p)*256 + d];
        }
        return;
    }

    // 64x64 tile: W[K][256] fp32 -> swizzled bf16 chunks
    __shared__ short tile[64 * 65];
    const float* W; u16* Wt; int K32, bk, bn;
    if (b < 96)       { const int r = b/32, tt = b%32;
                        W = (r==0)?Wmp1:((r==1)?Wmp2:Wmp3);
                        Wt = (u16*)(ws + WOFF_WT) + (size_t)r*256*512;
                        K32 = 16;  bk = tt/4;  bn = tt%4; }
    else if (b < 160) { const int tt = b-96;
                        W = Wagg; Wt = (u16*)(ws + WOFF_WAGG);
                        K32 = 32; bk = tt/4;  bn = tt%4; }
    else if (b < 176) { const int tt = b-160;
                        W = Wmu;  Wt = (u16*)(ws + WOFF_WMU);
                        K32 = 8;  bk = tt/4;  bn = tt%4; }
    else              { const int tt = b-176;
                        W = Wvar; Wt = (u16*)(ws + WOFF_WVAR);
                        K32 = 8;  bk = tt/4;  bn = tt%4; }

    const int r = t >> 6, c = t & 63;
    const int k0 = bk*64, n0 = bn*64;
    #pragma unroll
    for (int i = 0; i < 16; ++i) {
        const int kk = r + i*4;
        tile[kk*65 + c] = (short)f2us(W[(size_t)(k0 + kk)*256 + n0 + c]);
    }
    __syncthreads();

    const int lane = t >> 2;
    const int j0   = (t & 3) * 2;
    const int quad = lane >> 4, l16 = lane & 15;
    #pragma unroll
    for (int dk = 0; dk < 2; ++dk) {
        const int ktf = bk*2 + dk;
        #pragma unroll
        for (int nt = 0; nt < 4; ++nt) {
            const int chunk = (bn*K32 + ktf)*4 + nt;
            u32* dst = (u32*)(Wt + (size_t)chunk*512);
            const int kl = dk*32 + quad*8 + j0;
            const int nl = nt*16 + l16;
            const u32 v = (u32)(u16)tile[kl*65 + nl] |
                          ((u32)(u16)tile[(kl+1)*65 + nl] << 16);
            dst[t] = v;
        }
    }
}

// ---------------------------------------------------------------------------
// Graph kernel: TWO graphs per block (shared W stream -> half L2 traffic,
// 2x MFMA per W load). 1024 blocks, 4 waves, 3 blocks/CU.
// ---------------------------------------------------------------------------
__global__ __launch_bounds__(256, 3) void graph_kernel(
    const float* __restrict__ geometry,
    const void* __restrict__ semantic,
    const void* __restrict__ edge_index,
    const float* __restrict__ bmp1, const float* __restrict__ bmp2,
    const float* __restrict__ bmp3,
    const char* __restrict__ ws, u16* __restrict__ G,
    const int* __restrict__ flags)
{
    __shared__ __align__(16) short Ahi[2][32*SA];  // 33280 B (rows 0..7 alias cntC)
    __shared__ __align__(16) short Shi[2][32*SS];  // 5120 B
    __shared__ __align__(16) short Slo[2][32*SS];  // 5120 B
    __shared__ int   cntN[2][32];
    __shared__ float geo_l[2][NB*5];
    __shared__ int   sem_l[2][NB];

    const int tid  = threadIdx.x;
    const int g0   = blockIdx.x * 2;
    const int wave = tid >> 6, lane = tid & 63;
    const int l16  = lane & 15, quad = lane >> 4;

    const int i64 = flags[0];
    const u16* WtAll = (const u16*)(ws + WOFF_WT);
    const float* tab = (const float*)(ws + WOFF_TAB);

    // ---- zero / stage ----
    {
        i4 z = {0, 0, 0, 0};
        #pragma unroll
        for (int gg = 0; gg < 2; ++gg) {
            ((i4*)&Ahi[gg][0])[tid] = z;                      // cntC overlay 4096 B
            if (tid < 65) ((i4*)&Ahi[gg][30*SA])[tid] = z;    // rows 30,31
            if (tid < 160) { ((i4*)&Shi[gg][0])[tid] = z; ((i4*)&Slo[gg][0])[tid] = z; }
            if (tid < 32) cntN[gg][tid] = 0;
            if (tid < NB*5) geo_l[gg][tid] = geometry[(size_t)(g0+gg)*NB*5 + tid];
            if (tid < NB)   sem_l[gg][tid] = ldidx(semantic, (g0+gg)*NB + tid, i64);
        }
    }
    __syncthreads();

    // ---- edge counts ----
    if (tid < EPG) {
        #pragma unroll
        for (int gg = 0; gg < 2; ++gg) {
            int* cntC = (int*)&Ahi[gg][0];
            const long long e = (long long)(g0+gg)*EPG + tid;
            const int s  = ldidx(edge_index, e,                  i64) - (g0+gg)*NB;
            const int dd = ldidx(edge_index, (long long)NEg + e, i64) - (g0+gg)*NB;
            atomicAdd(&cntC[dd*32 + s], 1);
            atomicAdd(&cntN[gg][dd], 1);
        }
    }
    __syncthreads();

    // ---- S = cnt_nm / cnt_n, exact hi/lo split ----
    #pragma unroll
    for (int gg = 0; gg < 2; ++gg) {
        const int* cntC = (const int*)&Ahi[gg][0];
        for (int i = tid; i < 960; i += 256) {
            const int n = i >> 5, m = i & 31;
            const int c = cntC[n*32 + m], cn = cntN[gg][n];
            const float v = (cn > 0) ? (float)c / (float)cn : 0.f;
            const u16 hi = f2us(v);
            Shi[gg][n*SS + m] = (short)hi;
            Slo[gg][n*SS + m] = (short)f2us(v - us2f(hi));
        }
    }
    __syncthreads();   // cntC reads done before encoder overwrites rows 0..7

    // ---- encoder via exact tables; thread = col d ----
    {
        const int d = tid;
        const float m0 = tab[0*256+d], m1 = tab[1*256+d], m2 = tab[2*256+d],
                    m3 = tab[3*256+d], m4 = tab[4*256+d];
        const float cD = tab[1280 + d];
        #pragma unroll
        for (int gg = 0; gg < 2; ++gg) {
            float gmax = 0.f;
            for (int n = 0; n < NB; ++n) {
                const int s = sem_l[gg][n];
                float a = cD + tab[1536 + s*256 + d] + tab[4352 + n*256 + d];
                a = fmaf(geo_l[gg][n*5+0], m0, a); a = fmaf(geo_l[gg][n*5+1], m1, a);
                a = fmaf(geo_l[gg][n*5+2], m2, a); a = fmaf(geo_l[gg][n*5+3], m3, a);
                a = fmaf(geo_l[gg][n*5+4], m4, a);
                const float v = fmaxf(a, 0.f);
                Ahi[gg][n*SA + d] = (short)f2us(v);
                gmax = fmaxf(gmax, v);
            }
            G[(size_t)(g0+gg)*1024 + d] = f2us(gmax);   // g0
        }
    }
    __syncthreads();

    // ---- per-lane row masks ----
    unsigned rmask[2] = {0, 0};
    #pragma unroll
    for (int gg = 0; gg < 2; ++gg)
        #pragma unroll
        for (int mt = 0; mt < 2; ++mt)
            #pragma unroll
            for (int i = 0; i < 4; ++i) {
                const int row = mt*16 + quad*4 + i;
                if (row < NB && cntN[gg][row] > 0) rmask[gg] |= 1u << (mt*4 + i);
            }

    // S fragments (constant across rounds)
    bf8 sh[2][2], sl[2][2];
    #pragma unroll
    for (int gg = 0; gg < 2; ++gg)
        #pragma unroll
        for (int mo = 0; mo < 2; ++mo) {
            sh[gg][mo] = *(const bf8*)&Shi[gg][(mo*16 + l16)*SS + quad*8];
            sl[gg][mo] = *(const bf8*)&Slo[gg][(mo*16 + l16)*SS + quad*8];
        }
    const int srcbase = ((quad & 1) << 5) | l16;
    const int mtsel   = quad >> 1;

    // ---- 3 message-passing rounds ----
    for (int r = 0; r < 3; ++r) {
        const u16* Wsw = WtAll + (size_t)r*131072;

        f4 C1[2][2][4], P[2][2][4];   // [gg][mt][nt]
        #pragma unroll
        for (int gg = 0; gg < 2; ++gg)
            #pragma unroll
            for (int mt = 0; mt < 2; ++mt)
                #pragma unroll
                for (int nt = 0; nt < 4; ++nt) {
                    C1[gg][mt][nt] = (f4){0.f, 0.f, 0.f, 0.f};
                    P [gg][mt][nt] = (f4){0.f, 0.f, 0.f, 0.f};
                }

        #pragma unroll
        for (int kt = 0; kt < 8; ++kt) {
            bf8 ah[2][2];
            #pragma unroll
            for (int gg = 0; gg < 2; ++gg)
                #pragma unroll
                for (int mt = 0; mt < 2; ++mt)
                    ah[gg][mt] = *(const bf8*)&Ahi[gg][(mt*16 + l16)*SA + kt*32 + quad*8];
            #pragma unroll
            for (int nt = 0; nt < 4; ++nt) {
                const bf8 bt = *(const bf8*)&Wsw[(size_t)(((wave*16 + kt  )*4 + nt))*512 + lane*8];
                const bf8 bb = *(const bf8*)&Wsw[(size_t)(((wave*16 + kt+8)*4 + nt))*512 + lane*8];
                #pragma unroll
                for (int gg = 0; gg < 2; ++gg)
                    #pragma unroll
                    for (int mt = 0; mt < 2; ++mt) {
                        C1[gg][mt][nt] = __builtin_amdgcn_mfma_f32_16x16x32_bf16(ah[gg][mt], bt, C1[gg][mt][nt], 0, 0, 0);
                        P [gg][mt][nt] = __builtin_amdgcn_mfma_f32_16x16x32_bf16(ah[gg][mt], bb, P [gg][mt][nt], 0, 0, 0);
                    }
            }
        }

        // S @ P per graph (B-frags in-register via shfl)
        #pragma unroll
        for (int gg = 0; gg < 2; ++gg) {
            unsigned pk[2][4][2];
            #pragma unroll
            for (int mt = 0; mt < 2; ++mt)
                #pragma unroll
                for (int nt = 0; nt < 4; ++nt) {
                    pk[mt][nt][0] = (u32)f2us(P[gg][mt][nt][0]) | ((u32)f2us(P[gg][mt][nt][1]) << 16);
                    pk[mt][nt][1] = (u32)f2us(P[gg][mt][nt][2]) | ((u32)f2us(P[gg][mt][nt][3]) << 16);
                }
            #pragma unroll
            for (int nt = 0; nt < 4; ++nt) {
                union { bf8 v; u32 u[4]; } bf_;
                #pragma unroll
                for (int t2 = 0; t2 < 4; ++t2) {
                    const int src = srcbase + ((t2 >> 1) << 4);
                    const u32 v0 = __shfl(pk[0][nt][t2 & 1], src, 64);
                    const u32 v1 = __shfl(pk[1][nt][t2 & 1], src, 64);
                    bf_.u[t2] = mtsel ? v1 : v0;
                }
                #pragma unroll
                for (int mo = 0; mo < 2; ++mo) {
                    C1[gg][mo][nt] = __builtin_amdgcn_mfma_f32_16x16x32_bf16(sh[gg][mo], bf_.v, C1[gg][mo][nt], 0, 0, 0);
                    C1[gg][mo][nt] = __builtin_amdgcn_mfma_f32_16x16x32_bf16(sl[gg][mo], bf_.v, C1[gg][mo][nt], 0, 0, 0);
                }
            }
        }
        __syncthreads();   // all A reads complete before epilogue overwrites

        // epilogue
        const float* br = (r == 0) ? bmp1 : ((r == 1) ? bmp2 : bmp3);
        #pragma unroll
        for (int nt = 0; nt < 4; ++nt) {
            const int col = wave*64 + nt*16 + l16;
            const float bias = br[col];
            #pragma unroll
            for (int gg = 0; gg < 2; ++gg) {
                float cmax = 0.f;
                #pragma unroll
                for (int mt = 0; mt < 2; ++mt)
                    #pragma unroll
                    for (int i = 0; i < 4; ++i) {
                        const int row = mt*16 + quad*4 + i;
                        float v = fmaxf(C1[gg][mt][nt][i] + bias, 0.f);
                        if (!((rmask[gg] >> (mt*4 + i)) & 1u)) v = 0.f;
                        Ahi[gg][row*SA + col] = (short)f2us(v);
                        cmax = fmaxf(cmax, v);
                    }
                cmax = fmaxf(cmax, __shfl_xor(cmax, 16, 64));
                cmax = fmaxf(cmax, __shfl_xor(cmax, 32, 64));
                if (quad == 0)
                    G[(size_t)(g0+gg)*1024 + (r+1)*256 + col] = f2us(cmax);
            }
        }
        __syncthreads();
    }
}

// ---------------------------------------------------------------------------
// Heads: 256 blocks x 8 graphs (M=8 dup to 16). W reads coalesced.
// ---------------------------------------------------------------------------
__global__ __launch_bounds__(256, 4) void head_kernel(
    const char* __restrict__ ws, const u16* __restrict__ G,
    const float* __restrict__ bagg, const float* __restrict__ bmu,
    const float* __restrict__ bvar, float* __restrict__ out)
{
    __shared__ __align__(16) short Gs[8*SG];     // 16512 B
    __shared__ __align__(16) short Lhi[16*SL];
    __shared__ __align__(16) short Llo[16*SL];

    const int tid  = threadIdx.x;
    const int wave = tid >> 6, lane = tid & 63;
    const int l16  = lane & 15, quad = lane >> 4;
    const int g0   = blockIdx.x * 8;

    const u16* WtA = (const u16*)(ws + WOFF_WAGG);
    const u16* WtM = (const u16*)(ws + WOFF_WMU);
    const u16* WtV = (const u16*)(ws + WOFF_WVAR);

    #pragma unroll
    for (int rr = 0; rr < 8; ++rr) {
        ((u32*)&Gs[rr*SG])[tid]       = ((const u32*)&G[(size_t)(g0+rr)*1024])[tid];
        ((u32*)&Gs[rr*SG])[tid + 256] = ((const u32*)&G[(size_t)(g0+rr)*1024])[tid + 256];
    }
    __syncthreads();

    // GEMM1: latent[8][256] = G[8][1024] @ Wagg
    f4 acc[4];
    #pragma unroll
    for (int nt = 0; nt < 4; ++nt) acc[nt] = (f4){0.f, 0.f, 0.f, 0.f};

    #pragma unroll 8
    for (int kt = 0; kt < 32; ++kt) {
        const bf8 ah = *(const bf8*)&Gs[(l16 & 7)*SG + kt*32 + quad*8];
        #pragma unroll
        for (int nt = 0; nt < 4; ++nt) {
            const bf8 b = *(const bf8*)&WtA[(size_t)((wave*32 + kt)*4 + nt)*512 + lane*8];
            acc[nt] = __builtin_amdgcn_mfma_f32_16x16x32_bf16(ah, b, acc[nt], 0, 0, 0);
        }
    }
    #pragma unroll
    for (int nt = 0; nt < 4; ++nt) {
        const int col = wave*64 + nt*16 + l16;
        const float bias = bagg[col];
        #pragma unroll
        for (int i = 0; i < 4; ++i) {
            const int row = quad*4 + i;
            const float v = acc[nt][i] + bias;
            const u16 hi = f2us(v);
            Lhi[row*SL + col] = (short)hi;
            Llo[row*SL + col] = (short)f2us(v - us2f(hi));
        }
    }
    __syncthreads();

    // GEMM2: mu / log_var
    f4 am[4], av[4];
    #pragma unroll
    for (int nt = 0; nt < 4; ++nt) {
        am[nt] = (f4){0.f, 0.f, 0.f, 0.f};
        av[nt] = (f4){0.f, 0.f, 0.f, 0.f};
    }
    #pragma unroll
    for (int kt = 0; kt < 8; ++kt) {
        const bf8 ah = *(const bf8*)&Lhi[l16*SL + kt*32 + quad*8];
        const bf8 al = *(const bf8*)&Llo[l16*SL + kt*32 + quad*8];
        #pragma unroll
        for (int nt = 0; nt < 4; ++nt) {
            const bf8 bm_ = *(const bf8*)&WtM[(size_t)((wave*8 + kt)*4 + nt)*512 + lane*8];
            const bf8 bv_ = *(const bf8*)&WtV[(size_t)((wave*8 + kt)*4 + nt)*512 + lane*8];
            am[nt] = __builtin_amdgcn_mfma_f32_16x16x32_bf16(ah, bm_, am[nt], 0, 0, 0);
            am[nt] = __builtin_amdgcn_mfma_f32_16x16x32_bf16(al, bm_, am[nt], 0, 0, 0);
            av[nt] = __builtin_amdgcn_mfma_f32_16x16x32_bf16(ah, bv_, av[nt], 0, 0, 0);
            av[nt] = __builtin_amdgcn_mfma_f32_16x16x32_bf16(al, bv_, av[nt], 0, 0, 0);
        }
    }
    #pragma unroll
    for (int nt = 0; nt < 4; ++nt) {
        const int col = wave*64 + nt*16 + l16;
        const float b1 = bmu[col], b2 = bvar[col];
        #pragma unroll
        for (int i = 0; i < 4; ++i) {
            const int r = quad*4 + i;
            if (r < 8) {
                const int row = g0 + r;
                out[(size_t)row*256 + col]          = am[nt][i] + b1;
                out[524288 + (size_t)row*256 + col] = av[nt][i] + b2;
            }
        }
    }
}

extern "C" void kernel_launch(void* const* d_in, const int* in_sizes, int n_in,
                              void* d_out, int out_size, void* d_ws, size_t ws_size,
                              hipStream_t stream)
{
    const float* geometry  = (const float*)d_in[0];
    const void*  semantic  = d_in[1];
    const void*  edge_ix   = d_in[2];
    const float* W_geo = (const float*)d_in[4];
    const float* b_geo = (const float*)d_in[5];
    const float* emb   = (const float*)d_in[6];
    const float* W_lot = (const float*)d_in[7];
    const float* b_lot = (const float*)d_in[8];
    const float* Wmp1  = (const float*)d_in[9];
    const float* bmp1  = (const float*)d_in[10];
    const float* Wmp2  = (const float*)d_in[11];
    const float* bmp2  = (const float*)d_in[12];
    const float* Wmp3  = (const float*)d_in[13];
    const float* bmp3  = (const float*)d_in[14];
    const float* Wagg  = (const float*)d_in[15];
    const float* bagg  = (const float*)d_in[16];
    const float* Wmu   = (const float*)d_in[17];
    const float* bmu   = (const float*)d_in[18];
    const float* Wvar  = (const float*)d_in[19];
    const float* bvar  = (const float*)d_in[20];

    char* ws    = (char*)d_ws;
    int*  flags = (int*)(ws + WOFF_FLAG);
    u16*  G     = (u16*)(ws + WOFF_G);

    prep_kernel<<<210, 256, 0, stream>>>(Wmp1, Wmp2, Wmp3, Wagg, Wmu, Wvar,
                                         W_geo, b_geo, emb, W_lot, b_lot,
                                         edge_ix, semantic, ws, flags);
    graph_kernel<<<BG/2, 256, 0, stream>>>(geometry, semantic, edge_ix,
                                           bmp1, bmp2, bmp3, ws, G, flags);
    head_kernel<<<256, 256, 0, stream>>>(ws, G, bagg, bmu, bvar, (float*)d_out);
}

// Round 14
// 222.816 us; speedup vs baseline: 1.5303x; 1.5303x over previous
//
#include <hip/hip_runtime.h>

typedef unsigned short u16;
typedef unsigned int u32;
typedef __attribute__((ext_vector_type(8))) short bf8;   // 8 bf16 (4 VGPRs)
typedef __attribute__((ext_vector_type(4))) float f4;    // MFMA C/D frag
typedef __attribute__((ext_vector_type(4))) int i4;

#define NB  30
#define BG  2048
#define EPG 240
#define NEg (BG*EPG)
#define SA  260     // A row stride (shorts): 130 dw -> uniform 2-way banks
#define SS  40      // S row stride
#define SL  264     // latent row stride (heads)
#define SG  1032    // head G-stage row stride (shorts)

// workspace offsets (bytes). W tensors fragment-major (swizzled):
// chunk(wslice,ktf,nt) = ((wslice*(K/32)+ktf)*4+nt)*512 u16, elem = lane*8+j,
// value = W^T[wslice*64+nt*16+(lane&15)][ktf*32+(lane>>4)*8+j]
#define WOFF_WT    0                         // [3][256][512] bf16
#define WOFF_WAGG  786432                    // [256][1024] bf16
#define WOFF_WMU   (786432+524288)           // [256][256] bf16
#define WOFF_WVAR  (786432+524288+131072)
#define WOFF_TAB   (786432+524288+262144)    // fp32 tables: 12032 floats
#define WOFF_G     (WOFF_TAB + 48128)        // g bf16 [2048][1024]
#define WOFF_FLAG  (WOFF_G + 4194304)        // 2 ints

__device__ __forceinline__ float us2f(u16 u) {
    union { u32 i; float f; } v; v.i = ((u32)u) << 16; return v.f;
}
__device__ __forceinline__ u16 f2us(float f) {
    union { float f; u32 u; } v; v.f = f;
    u32 u = v.u;
    return (u16)((u + 0x7FFFu + ((u >> 16) & 1u)) >> 16);   // RNE
}
__device__ __forceinline__ int ldidx(const void* p, long long i, int i64) {
    return i64 ? (int)((const long long*)p)[i] : ((const int*)p)[i];
}

// ---------------------------------------------------------------------------
// Prep (210 blocks): tile transposes -> swizzled fragment-major bf16,
// fp32 encoder tables (192..208), dtype probe (209).
// ---------------------------------------------------------------------------
__global__ __launch_bounds__(256) void prep_kernel(
    const float* __restrict__ Wmp1, const float* __restrict__ Wmp2,
    const float* __restrict__ Wmp3, const float* __restrict__ Wagg,
    const float* __restrict__ Wmu,  const float* __restrict__ Wvar,
    const float* __restrict__ W_geo, const float* __restrict__ b_geo,
    const float* __restrict__ emb,   const float* __restrict__ W_lot,
    const float* __restrict__ b_lot,
    const void* __restrict__ edge,  const void* __restrict__ semA,
    char* __restrict__ ws, int* __restrict__ flags)
{
    const int t = threadIdx.x;
    const int b = blockIdx.x;

    if (b == 209) {                    // probe
        if (t == 0) {
            const int* e32 = (const int*)edge;
            int zc = 0;
            for (int j = 1; j <= 31; j += 2) if (e32[j] == 0) zc++;
            flags[0] = (zc == 16) ? 1 : 0;
            flags[1] = 0;
        }
        return;
    }

    if (b >= 192) {                    // tables (exact fp32 algebra)
        float* tab = (float*)(ws + WOFF_TAB);
        const int d = t, b2 = b - 192;
        if (b2 < 5) {
            float a = 0.f;
            #pragma unroll 8
            for (int k = 0; k < 256; ++k)
                a = fmaf(W_geo[b2*256 + k], W_lot[k*256 + d], a);
            tab[b2*256 + d] = a;
        } else if (b2 < 16) {
            const int s = b2 - 5;
            float a = 0.f;
            #pragma unroll 8
            for (int k = 0; k < 256; ++k)
                a = fmaf(emb[s*256 + k], W_lot[(256 + k)*256 + d], a);
            tab[1536 + s*256 + d] = a;
        } else {
            float a = b_lot[d];
            #pragma unroll 8
            for (int k = 0; k < 256; ++k)
                a = fmaf(b_geo[k], W_lot[k*256 + d], a);
            tab[1280 + d] = a;
            for (int p = 0; p < NB; ++p)
                tab[4352 + p*256 + d] = W_lot[(512 + p)*256 + d];
        }
        return;
    }

    // 64x64 tile: W[K][256] fp32 -> swizzled bf16 chunks
    __shared__ short tile[64 * 65];
    const float* W; u16* Wt; int K32, bk, bn;
    if (b < 96)       { const int r = b/32, tt = b%32;
                        W = (r==0)?Wmp1:((r==1)?Wmp2:Wmp3);
                        Wt = (u16*)(ws + WOFF_WT) + (size_t)r*256*512;
                        K32 = 16;  bk = tt/4;  bn = tt%4; }
    else if (b < 160) { const int tt = b-96;
                        W = Wagg; Wt = (u16*)(ws + WOFF_WAGG);
                        K32 = 32; bk = tt/4;  bn = tt%4; }
    else if (b < 176) { const int tt = b-160;
                        W = Wmu;  Wt = (u16*)(ws + WOFF_WMU);
                        K32 = 8;  bk = tt/4;  bn = tt%4; }
    else              { const int tt = b-176;
                        W = Wvar; Wt = (u16*)(ws + WOFF_WVAR);
                        K32 = 8;  bk = tt/4;  bn = tt%4; }

    const int r = t >> 6, c = t & 63;
    const int k0 = bk*64, n0 = bn*64;
    #pragma unroll
    for (int i = 0; i < 16; ++i) {
        const int kk = r + i*4;
        tile[kk*65 + c] = (short)f2us(W[(size_t)(k0 + kk)*256 + n0 + c]);
    }
    __syncthreads();

    const int lane = t >> 2;
    const int j0   = (t & 3) * 2;
    const int quad = lane >> 4, l16 = lane & 15;
    #pragma unroll
    for (int dk = 0; dk < 2; ++dk) {
        const int ktf = bk*2 + dk;
        #pragma unroll
        for (int nt = 0; nt < 4; ++nt) {
            const int chunk = (bn*K32 + ktf)*4 + nt;
            u32* dst = (u32*)(Wt + (size_t)chunk*512);
            const int kl = dk*32 + quad*8 + j0;
            const int nl = nt*16 + l16;
            const u32 v = (u32)(u16)tile[kl*65 + nl] |
                          ((u32)(u16)tile[(kl+1)*65 + nl] << 16);
            dst[t] = v;
        }
    }
}

// ---------------------------------------------------------------------------
// Graph kernel: TWO graphs per block via wave split (512 threads).
// Waves 0-3 -> graph A, waves 4-7 -> graph B. Wave w and w+4 stream the SAME
// W fragments in lockstep -> L1/L2-local reuse, no extra registers (per-wave
// code identical to R12's proven no-spill layout).
// ---------------------------------------------------------------------------
__global__ __launch_bounds__(512, 4) void graph_kernel(
    const float* __restrict__ geometry,
    const void* __restrict__ semantic,
    const void* __restrict__ edge_index,
    const float* __restrict__ bmp1, const float* __restrict__ bmp2,
    const float* __restrict__ bmp3,
    const char* __restrict__ ws, u16* __restrict__ G,
    const int* __restrict__ flags)
{
    __shared__ __align__(16) short Ahi[2][32*SA];  // 33280 B (rows 0..7 alias cntC)
    __shared__ __align__(16) short Shi[2][32*SS];  // 5120 B
    __shared__ __align__(16) short Slo[2][32*SS];  // 5120 B
    __shared__ int   cntN[2][32];
    __shared__ float geo_l[2][NB*5];
    __shared__ int   sem_l[2][NB];

    const int tid  = threadIdx.x;
    const int g0   = blockIdx.x * 2;
    const int wave = tid >> 6, lane = tid & 63;
    const int l16  = lane & 15, quad = lane >> 4;
    const int gg   = wave >> 2;        // this wave's graph
    const int ws4  = wave & 3;         // this wave's W slice / col range
    const int t2   = tid & 255;        // index within half
    const int gh   = tid >> 8;         // this thread's graph (staging phases)

    const int i64 = flags[0];
    const u16* WtAll = (const u16*)(ws + WOFF_WT);
    const float* tab = (const float*)(ws + WOFF_TAB);

    // ---- zero / stage (each 256-thread half owns one graph) ----
    {
        i4 z = {0, 0, 0, 0};
        ((i4*)&Ahi[gh][0])[t2] = z;                       // cntC overlay 4096 B
        if (t2 < 65) ((i4*)&Ahi[gh][30*SA])[t2] = z;      // rows 30,31
        if (t2 < 160) { ((i4*)&Shi[gh][0])[t2] = z; ((i4*)&Slo[gh][0])[t2] = z; }
        if (t2 < 32) cntN[gh][t2] = 0;
        if (t2 < NB*5) geo_l[gh][t2] = geometry[(size_t)(g0+gh)*NB*5 + t2];
        if (t2 < NB)   sem_l[gh][t2] = ldidx(semantic, (g0+gh)*NB + t2, i64);
    }
    __syncthreads();

    // ---- edge counts ----
    if (t2 < EPG) {
        int* cntC = (int*)&Ahi[gh][0];
        const long long e = (long long)(g0+gh)*EPG + t2;
        const int s  = ldidx(edge_index, e,                  i64) - (g0+gh)*NB;
        const int dd = ldidx(edge_index, (long long)NEg + e, i64) - (g0+gh)*NB;
        atomicAdd(&cntC[dd*32 + s], 1);
        atomicAdd(&cntN[gh][dd], 1);
    }
    __syncthreads();

    // ---- S = cnt_nm / cnt_n, exact hi/lo split ----
    {
        const int* cntC = (const int*)&Ahi[gh][0];
        for (int i = t2; i < 960; i += 256) {
            const int n = i >> 5, m = i & 31;
            const int c = cntC[n*32 + m], cn = cntN[gh][n];
            const float v = (cn > 0) ? (float)c / (float)cn : 0.f;
            const u16 hi = f2us(v);
            Shi[gh][n*SS + m] = (short)hi;
            Slo[gh][n*SS + m] = (short)f2us(v - us2f(hi));
        }
    }
    __syncthreads();   // cntC reads done before encoder overwrites rows 0..7

    // ---- encoder via exact tables; thread = (graph gh, col t2) ----
    {
        const int d = t2;
        const float m0 = tab[0*256+d], m1 = tab[1*256+d], m2 = tab[2*256+d],
                    m3 = tab[3*256+d], m4 = tab[4*256+d];
        const float cD = tab[1280 + d];
        float gmax = 0.f;
        for (int n = 0; n < NB; ++n) {
            const int s = sem_l[gh][n];
            float a = cD + tab[1536 + s*256 + d] + tab[4352 + n*256 + d];
            a = fmaf(geo_l[gh][n*5+0], m0, a); a = fmaf(geo_l[gh][n*5+1], m1, a);
            a = fmaf(geo_l[gh][n*5+2], m2, a); a = fmaf(geo_l[gh][n*5+3], m3, a);
            a = fmaf(geo_l[gh][n*5+4], m4, a);
            const float v = fmaxf(a, 0.f);
            Ahi[gh][n*SA + d] = (short)f2us(v);
            gmax = fmaxf(gmax, v);
        }
        G[(size_t)(g0+gh)*1024 + d] = f2us(gmax);   // g0
    }
    __syncthreads();

    // ---- per-lane row mask (this wave's graph) ----
    unsigned rmask = 0;
    #pragma unroll
    for (int mt = 0; mt < 2; ++mt)
        #pragma unroll
        for (int i = 0; i < 4; ++i) {
            const int row = mt*16 + quad*4 + i;
            if (row < NB && cntN[gg][row] > 0) rmask |= 1u << (mt*4 + i);
        }

    // S fragments (this wave's graph; constant across rounds)
    bf8 sh[2], sl[2];
    #pragma unroll
    for (int mo = 0; mo < 2; ++mo) {
        sh[mo] = *(const bf8*)&Shi[gg][(mo*16 + l16)*SS + quad*8];
        sl[mo] = *(const bf8*)&Slo[gg][(mo*16 + l16)*SS + quad*8];
    }
    const int srcbase = ((quad & 1) << 5) | l16;
    const int mtsel   = quad >> 1;

    // ---- 3 message-passing rounds ----
    for (int r = 0; r < 3; ++r) {
        const u16* Wsw = WtAll + (size_t)r*131072;

        f4 C1[2][4], P[2][4];
        #pragma unroll
        for (int mt = 0; mt < 2; ++mt)
            #pragma unroll
            for (int nt = 0; nt < 4; ++nt) {
                C1[mt][nt] = (f4){0.f, 0.f, 0.f, 0.f};
                P [mt][nt] = (f4){0.f, 0.f, 0.f, 0.f};
            }

        #pragma unroll
        for (int kt = 0; kt < 8; ++kt) {
            bf8 ah[2];
            #pragma unroll
            for (int mt = 0; mt < 2; ++mt)
                ah[mt] = *(const bf8*)&Ahi[gg][(mt*16 + l16)*SA + kt*32 + quad*8];
            #pragma unroll
            for (int nt = 0; nt < 4; ++nt) {
                const bf8 bt = *(const bf8*)&Wsw[(size_t)(((ws4*16 + kt  )*4 + nt))*512 + lane*8];
                const bf8 bb = *(const bf8*)&Wsw[(size_t)(((ws4*16 + kt+8)*4 + nt))*512 + lane*8];
                #pragma unroll
                for (int mt = 0; mt < 2; ++mt) {
                    C1[mt][nt] = __builtin_amdgcn_mfma_f32_16x16x32_bf16(ah[mt], bt, C1[mt][nt], 0, 0, 0);
                    P [mt][nt] = __builtin_amdgcn_mfma_f32_16x16x32_bf16(ah[mt], bb, P [mt][nt], 0, 0, 0);
                }
            }
        }

        // pack P to bf16 pairs
        unsigned pk[2][4][2];
        #pragma unroll
        for (int mt = 0; mt < 2; ++mt)
            #pragma unroll
            for (int nt = 0; nt < 4; ++nt) {
                pk[mt][nt][0] = (u32)f2us(P[mt][nt][0]) | ((u32)f2us(P[mt][nt][1]) << 16);
                pk[mt][nt][1] = (u32)f2us(P[mt][nt][2]) | ((u32)f2us(P[mt][nt][3]) << 16);
            }

        // C1 += S @ P (B-frags in-register via shfl)
        #pragma unroll
        for (int nt = 0; nt < 4; ++nt) {
            union { bf8 v; u32 u[4]; } bf_;
            #pragma unroll
            for (int t3 = 0; t3 < 4; ++t3) {
                const int src = srcbase + ((t3 >> 1) << 4);
                const u32 v0 = __shfl(pk[0][nt][t3 & 1], src, 64);
                const u32 v1 = __shfl(pk[1][nt][t3 & 1], src, 64);
                bf_.u[t3] = mtsel ? v1 : v0;
            }
            #pragma unroll
            for (int mo = 0; mo < 2; ++mo) {
                C1[mo][nt] = __builtin_amdgcn_mfma_f32_16x16x32_bf16(sh[mo], bf_.v, C1[mo][nt], 0, 0, 0);
                C1[mo][nt] = __builtin_amdgcn_mfma_f32_16x16x32_bf16(sl[mo], bf_.v, C1[mo][nt], 0, 0, 0);
            }
        }
        __syncthreads();   // all A reads complete before epilogue overwrites

        // epilogue
        const float* br = (r == 0) ? bmp1 : ((r == 1) ? bmp2 : bmp3);
        #pragma unroll
        for (int nt = 0; nt < 4; ++nt) {
            const int col = ws4*64 + nt*16 + l16;
            const float bias = br[col];
            float cmax = 0.f;
            #pragma unroll
            for (int mt = 0; mt < 2; ++mt)
                #pragma unroll
                for (int i = 0; i < 4; ++i) {
                    const int row = mt*16 + quad*4 + i;
                    float v = fmaxf(C1[mt][nt][i] + bias, 0.f);
                    if (!((rmask >> (mt*4 + i)) & 1u)) v = 0.f;
                    Ahi[gg][row*SA + col] = (short)f2us(v);
                    cmax = fmaxf(cmax, v);
                }
            cmax = fmaxf(cmax, __shfl_xor(cmax, 16, 64));
            cmax = fmaxf(cmax, __shfl_xor(cmax, 32, 64));
            if (quad == 0)
                G[(size_t)(g0+gg)*1024 + (r+1)*256 + col] = f2us(cmax);
        }
        __syncthreads();
    }
}

// ---------------------------------------------------------------------------
// Heads: 256 blocks x 8 graphs (M=8 dup to 16). W reads coalesced.
// ---------------------------------------------------------------------------
__global__ __launch_bounds__(256, 4) void head_kernel(
    const char* __restrict__ ws, const u16* __restrict__ G,
    const float* __restrict__ bagg, const float* __restrict__ bmu,
    const float* __restrict__ bvar, float* __restrict__ out)
{
    __shared__ __align__(16) short Gs[8*SG];     // 16512 B
    __shared__ __align__(16) short Lhi[16*SL];
    __shared__ __align__(16) short Llo[16*SL];

    const int tid  = threadIdx.x;
    const int wave = tid >> 6, lane = tid & 63;
    const int l16  = lane & 15, quad = lane >> 4;
    const int g0   = blockIdx.x * 8;

    const u16* WtA = (const u16*)(ws + WOFF_WAGG);
    const u16* WtM = (const u16*)(ws + WOFF_WMU);
    const u16* WtV = (const u16*)(ws + WOFF_WVAR);

    #pragma unroll
    for (int rr = 0; rr < 8; ++rr) {
        ((u32*)&Gs[rr*SG])[tid]       = ((const u32*)&G[(size_t)(g0+rr)*1024])[tid];
        ((u32*)&Gs[rr*SG])[tid + 256] = ((const u32*)&G[(size_t)(g0+rr)*1024])[tid + 256];
    }
    __syncthreads();

    // GEMM1: latent[8][256] = G[8][1024] @ Wagg
    f4 acc[4];
    #pragma unroll
    for (int nt = 0; nt < 4; ++nt) acc[nt] = (f4){0.f, 0.f, 0.f, 0.f};

    #pragma unroll 8
    for (int kt = 0; kt < 32; ++kt) {
        const bf8 ah = *(const bf8*)&Gs[(l16 & 7)*SG + kt*32 + quad*8];
        #pragma unroll
        for (int nt = 0; nt < 4; ++nt) {
            const bf8 b = *(const bf8*)&WtA[(size_t)((wave*32 + kt)*4 + nt)*512 + lane*8];
            acc[nt] = __builtin_amdgcn_mfma_f32_16x16x32_bf16(ah, b, acc[nt], 0, 0, 0);
        }
    }
    #pragma unroll
    for (int nt = 0; nt < 4; ++nt) {
        const int col = wave*64 + nt*16 + l16;
        const float bias = bagg[col];
        #pragma unroll
        for (int i = 0; i < 4; ++i) {
            const int row = quad*4 + i;
            const float v = acc[nt][i] + bias;
            const u16 hi = f2us(v);
            Lhi[row*SL + col] = (short)hi;
            Llo[row*SL + col] = (short)f2us(v - us2f(hi));
        }
    }
    __syncthreads();

    // GEMM2: mu / log_var
    f4 am[4], av[4];
    #pragma unroll
    for (int nt = 0; nt < 4; ++nt) {
        am[nt] = (f4){0.f, 0.f, 0.f, 0.f};
        av[nt] = (f4){0.f, 0.f, 0.f, 0.f};
    }
    #pragma unroll
    for (int kt = 0; kt < 8; ++kt) {
        const bf8 ah = *(const bf8*)&Lhi[l16*SL + kt*32 + quad*8];
        const bf8 al = *(const bf8*)&Llo[l16*SL + kt*32 + quad*8];
        #pragma unroll
        for (int nt = 0; nt < 4; ++nt) {
            const bf8 bm_ = *(const bf8*)&WtM[(size_t)((wave*8 + kt)*4 + nt)*512 + lane*8];
            const bf8 bv_ = *(const bf8*)&WtV[(size_t)((wave*8 + kt)*4 + nt)*512 + lane*8];
            am[nt] = __builtin_amdgcn_mfma_f32_16x16x32_bf16(ah, bm_, am[nt], 0, 0, 0);
            am[nt] = __builtin_amdgcn_mfma_f32_16x16x32_bf16(al, bm_, am[nt], 0, 0, 0);
            av[nt] = __builtin_amdgcn_mfma_f32_16x16x32_bf16(ah, bv_, av[nt], 0, 0, 0);
            av[nt] = __builtin_amdgcn_mfma_f32_16x16x32_bf16(al, bv_, av[nt], 0, 0, 0);
        }
    }
    #pragma unroll
    for (int nt = 0; nt < 4; ++nt) {
        const int col = wave*64 + nt*16 + l16;
        const float b1 = bmu[col], b2 = bvar[col];
        #pragma unroll
        for (int i = 0; i < 4; ++i) {
            const int r = quad*4 + i;
            if (r < 8) {
                const int row = g0 + r;
                out[(size_t)row*256 + col]          = am[nt][i] + b1;
                out[524288 + (size_t)row*256 + col] = av[nt][i] + b2;
            }
        }
    }
}

extern "C" void kernel_launch(void* const* d_in, const int* in_sizes, int n_in,
                              void* d_out, int out_size, void* d_ws, size_t ws_size,
                              hipStream_t stream)
{
    const float* geometry  = (const float*)d_in[0];
    const void*  semantic  = d_in[1];
    const void*  edge_ix   = d_in[2];
    const float* W_geo = (const float*)d_in[4];
    const float* b_geo = (const float*)d_in[5];
    const float* emb   = (const float*)d_in[6];
    const float* W_lot = (const float*)d_in[7];
    const float* b_lot = (const float*)d_in[8];
    const float* Wmp1  = (const float*)d_in[9];
    const float* bmp1  = (const float*)d_in[10];
    const float* Wmp2  = (const float*)d_in[11];
    const float* bmp2  = (const float*)d_in[12];
    const float* Wmp3  = (const float*)d_in[13];
    const float* bmp3  = (const float*)d_in[14];
    const float* Wagg  = (const float*)d_in[15];
    const float* bagg  = (const float*)d_in[16];
    const float* Wmu   = (const float*)d_in[17];
    const float* bmu   = (const float*)d_in[18];
    const float* Wvar  = (const float*)d_in[19];
    const float* bvar  = (const float*)d_in[20];

    char* ws    = (char*)d_ws;
    int*  flags = (int*)(ws + WOFF_FLAG);
    u16*  G     = (u16*)(ws + WOFF_G);

    prep_kernel<<<210, 256, 0, stream>>>(Wmp1, Wmp2, Wmp3, Wagg, Wmu, Wvar,
                                         W_geo, b_geo, emb, W_lot, b_lot,
                                         edge_ix, semantic, ws, flags);
    graph_kernel<<<BG/2, 512, 0, stream>>>(geometry, semantic, edge_ix,
                                           bmp1, bmp2, bmp3, ws, G, flags);
    head_kernel<<<256, 256, 0, stream>>>(ws, G, bagg, bmu, bvar, (float*)d_out);
}